// Round 1
// baseline (1039.550 us; speedup 1.0000x reference)
//
#include <hip/hip_runtime.h>

typedef __bf16 bf16x8 __attribute__((ext_vector_type(8)));
typedef float f32x4 __attribute__((ext_vector_type(4)));

#define MFMA16(a, b, c) __builtin_amdgcn_mfma_f32_16x16x32_bf16(a, b, c, 0, 0, 0)

// async global->LDS, 16B per lane; LDS dest is wave-uniform base + lane*16
__device__ __forceinline__ void gload_lds16(const void* g, void* l) {
  __builtin_amdgcn_global_load_lds(
      (const __attribute__((address_space(1))) void*)(unsigned long long)g,
      (__attribute__((address_space(3))) void*)(unsigned int)(unsigned long long)l,
      16, 0, 0);
}

// ---------------- K0: convert 3x512x512 fp32 weights -> bf16 ----------------
__global__ void cvt_w_kernel(const float* __restrict__ wq, const float* __restrict__ wk,
                             const float* __restrict__ wv, __bf16* __restrict__ w) {
  int i = blockIdx.x * 256 + threadIdx.x;  // grid 1024 -> 262144
  w[i]          = (__bf16)wq[i];
  w[i + 262144] = (__bf16)wk[i];
  w[i + 524288] = (__bf16)wv[i];
}

// ---------------- K1: LayerNorm rows of 512, fp32 -> bf16 -------------------
// rows 0..98303 from x, 98304..196607 from cross_x; one wave per row
__global__ __launch_bounds__(256) void ln_kernel(
    const float* __restrict__ x, const float* __restrict__ cx,
    const float* __restrict__ g, const float* __restrict__ bet,
    __bf16* __restrict__ xn) {
  int wave = threadIdx.x >> 6, lane = threadIdx.x & 63;
  long row = (long)blockIdx.x * 4 + wave;
  const float* src = (row < 98304) ? (x + row * 512) : (cx + (row - 98304) * 512);
  const f32x4* p = (const f32x4*)(src + lane * 8);
  f32x4 a = p[0], b = p[1];
  float s  = a[0] + a[1] + a[2] + a[3] + b[0] + b[1] + b[2] + b[3];
  float s2 = a[0]*a[0] + a[1]*a[1] + a[2]*a[2] + a[3]*a[3]
           + b[0]*b[0] + b[1]*b[1] + b[2]*b[2] + b[3]*b[3];
  for (int d = 1; d < 64; d <<= 1) { s += __shfl_xor(s, d, 64); s2 += __shfl_xor(s2, d, 64); }
  float mean = s * (1.0f / 512.0f);
  float var  = s2 * (1.0f / 512.0f) - mean * mean;
  float rs = rsqrtf(var + 1e-5f);
  const f32x4* gp = (const f32x4*)(g + lane * 8);
  const f32x4* bp = (const f32x4*)(bet + lane * 8);
  f32x4 g0 = gp[0], g1 = gp[1], b0 = bp[0], b1 = bp[1];
  bf16x8 o;
  for (int j = 0; j < 4; ++j) o[j]     = (__bf16)((a[j] - mean) * rs * g0[j] + b0[j]);
  for (int j = 0; j < 4; ++j) o[4 + j] = (__bf16)((b[j] - mean) * rs * g1[j] + b1[j]);
  *(bf16x8*)(xn + row * 512 + lane * 8) = o;
}

// ---------------- K2: QKV projection GEMM (NT), 128x128 tile, BK=64 ---------
// z=0: Q = xn @ Wq^T ; z=1: K = cn @ Wk^T ; z=2: V = cn @ Wv^T
__global__ __launch_bounds__(256) void gemm_qkv_kernel(
    const __bf16* __restrict__ act, const __bf16* __restrict__ w,
    __bf16* __restrict__ outqkv) {
  int z = blockIdx.z;
  const __bf16* A = act + (z ? (long)50331648 : 0);   // cn for K,V
  const __bf16* B = w + (long)z * 262144;
  __bf16* C = outqkv + (long)z * 50331648;
  int m0 = blockIdx.x * 128, n0 = blockIdx.y * 128;
  int tid = threadIdx.x, wave = tid >> 6, lane = tid & 63;
  int q4 = lane >> 4, cl = lane & 15;
  int wm = wave & 1, wn = wave >> 1;
  __shared__ __bf16 As[128 * 64];
  __shared__ __bf16 Bs[128 * 64];
  f32x4 acc[4][4] = {};
  for (int kb = 0; kb < 512; kb += 64) {
    for (int i = 0; i < 4; ++i) {
      int t = i * 256 + tid;
      int row = t >> 3;
      int col = (t & 7) * 8;
      gload_lds16(A + (long)(m0 + row) * 512 + kb + col, (char*)As + (i * 256 + wave * 64) * 16);
      gload_lds16(B + (long)(n0 + row) * 512 + kb + col, (char*)Bs + (i * 256 + wave * 64) * 16);
    }
    __syncthreads();
    for (int kc = 0; kc < 2; ++kc) {
      bf16x8 af[4], bfr[4];
      for (int mt = 0; mt < 4; ++mt)
        af[mt] = *(const bf16x8*)(As + (wm * 64 + mt * 16 + cl) * 64 + kc * 32 + q4 * 8);
      for (int nt = 0; nt < 4; ++nt)
        bfr[nt] = *(const bf16x8*)(Bs + (wn * 64 + nt * 16 + cl) * 64 + kc * 32 + q4 * 8);
      for (int mt = 0; mt < 4; ++mt)
        for (int nt = 0; nt < 4; ++nt)
          acc[mt][nt] = MFMA16(af[mt], bfr[nt], acc[mt][nt]);
    }
    __syncthreads();
  }
  for (int mt = 0; mt < 4; ++mt)
    for (int nt = 0; nt < 4; ++nt) {
      int row = m0 + wm * 64 + mt * 16 + q4 * 4;
      int col = n0 + wn * 64 + nt * 16 + cl;
      for (int r = 0; r < 4; ++r)
        C[(long)(row + r) * 512 + col] = (__bf16)acc[mt][nt][r];
    }
}

// ---------------- K3: attention + softmax + residual + output ---------------
// one block per (b, n, h); rows gathered at stride 12288 in original layout
__global__ __launch_bounds__(256) void attn_kernel(
    const __bf16* __restrict__ Q, const __bf16* __restrict__ K,
    const __bf16* __restrict__ V, const float* __restrict__ x,
    float* __restrict__ out) {
  int blk = blockIdx.x;            // 16*24*8 = 3072
  int h = blk & 7;
  int rem = blk >> 3;
  int n_ = rem % 24;
  int b_ = rem / 24;
  long base = ((long)b_ * 6144 + n_) * 512 + h * 64;  // row stride over t is 12288
  const long ST = 12288;
  int tid = threadIdx.x, wave = tid >> 6, lane = tid & 63;
  int q4 = lane >> 4, cl = lane & 15;
  __shared__ __bf16 Vt[64][264];     // V transposed: [d][key], padded (+8) for LDS banks
  __shared__ __bf16 Pb[4][16][72];   // per-wave P chunk buffer, padded

  {  // stage V transposed: thread tid handles key row t = tid
    const __bf16* vrow = V + base + (long)tid * ST;
    for (int i = 0; i < 8; ++i) {
      bf16x8 v = *(const bf16x8*)(vrow + i * 8);
      for (int j = 0; j < 8; ++j) Vt[i * 8 + j][tid] = v[j];
    }
  }
  __syncthreads();

  for (int iter = 0; iter < 4; ++iter) {
    int mt = iter * 4 + wave;        // 16 m-tiles of 16 queries
    int tq = mt * 16;
    const __bf16* qrow = Q + base + (long)(tq + cl) * ST;  // A-frag: m = lane&15
    bf16x8 qa0 = *(const bf16x8*)(qrow + q4 * 8);
    bf16x8 qa1 = *(const bf16x8*)(qrow + 32 + q4 * 8);
    f32x4 s[16];
    for (int nt = 0; nt < 16; ++nt) {
      const __bf16* krow = K + base + (long)(nt * 16 + cl) * ST;  // B-frag: n = lane&15
      bf16x8 kb0 = *(const bf16x8*)(krow + q4 * 8);
      bf16x8 kb1 = *(const bf16x8*)(krow + 32 + q4 * 8);
      f32x4 a = {};
      a = MFMA16(qa0, kb0, a);
      a = MFMA16(qa1, kb1, a);
      s[nt] = a;
    }
    // softmax over 256 keys; C-layout: lane holds rows q4*4+r, col = key = nt*16+cl
    float mx[4], l[4];
    for (int r = 0; r < 4; ++r) {
      float m = -1e30f;
      for (int nt = 0; nt < 16; ++nt) m = fmaxf(m, s[nt][r]);
      for (int d = 1; d < 16; d <<= 1) m = fmaxf(m, __shfl_xor(m, d, 64));
      mx[r] = m;
    }
    for (int r = 0; r < 4; ++r) l[r] = 0.0f;
    const float c_exp = 0.125f * 1.44269504088896f;  // fold 1/sqrt(64) into exp2
    for (int nt = 0; nt < 16; ++nt)
      for (int r = 0; r < 4; ++r) {
        float p = exp2f((s[nt][r] - mx[r]) * c_exp);
        s[nt][r] = p;
        l[r] += p;
      }
    for (int r = 0; r < 4; ++r)
      for (int d = 1; d < 16; d <<= 1) l[r] += __shfl_xor(l[r], d, 64);

    // PV: chunk keys by 64; P C-layout -> A-layout via per-wave LDS roundtrip
    f32x4 o[4] = {};
    for (int ch = 0; ch < 4; ++ch) {
      for (int j = 0; j < 4; ++j)
        for (int r = 0; r < 4; ++r)
          Pb[wave][q4 * 4 + r][j * 16 + cl] = (__bf16)s[ch * 4 + j][r];
      __syncthreads();
      bf16x8 pa0 = *(const bf16x8*)(&Pb[wave][cl][0] + q4 * 8);
      bf16x8 pa1 = *(const bf16x8*)(&Pb[wave][cl][0] + 32 + q4 * 8);
      for (int dt = 0; dt < 4; ++dt) {
        bf16x8 vb0 = *(const bf16x8*)(&Vt[dt * 16 + cl][ch * 64] + q4 * 8);
        bf16x8 vb1 = *(const bf16x8*)(&Vt[dt * 16 + cl][ch * 64] + 32 + q4 * 8);
        o[dt] = MFMA16(pa0, vb0, o[dt]);
        o[dt] = MFMA16(pa1, vb1, o[dt]);
      }
      __syncthreads();
    }
    // epilogue: normalize, residual, store (original (b,t,n,c) layout)
    for (int dt = 0; dt < 4; ++dt)
      for (int r = 0; r < 4; ++r) {
        long addr = base + (long)(tq + q4 * 4 + r) * ST + dt * 16 + cl;
        out[addr] = x[addr] + o[dt][r] / l[r];
      }
  }
}

extern "C" void kernel_launch(void* const* d_in, const int* in_sizes, int n_in,
                              void* d_out, int out_size, void* d_ws, size_t ws_size,
                              hipStream_t stream) {
  const float* x     = (const float*)d_in[0];
  const float* cx    = (const float*)d_in[1];
  const float* gamma = (const float*)d_in[2];
  const float* beta  = (const float*)d_in[3];
  const float* Wq    = (const float*)d_in[4];
  const float* Wk    = (const float*)d_in[5];
  const float* Wv    = (const float*)d_in[6];
  float* out = (float*)d_out;
  char* ws = (char*)d_ws;

  // workspace layout (bytes):
  //   [0,            1572864)   Wqkv bf16  (3*512*512*2)
  //   [1572864,      202899456) xn|cn bf16 (2*98304*512*2)
  //   [202899456,    504889344) Q|K|V bf16 (3*98304*512*2)
  __bf16* Wb = (__bf16*)(ws);
  __bf16* xn = (__bf16*)(ws + 1572864);
  __bf16* Qb = (__bf16*)(ws + 202899456);
  __bf16* Kb = (__bf16*)(ws + 303562752);
  __bf16* Vb = (__bf16*)(ws + 404226048);

  cvt_w_kernel<<<1024, 256, 0, stream>>>(Wq, Wk, Wv, Wb);
  ln_kernel<<<49152, 256, 0, stream>>>(x, cx, gamma, beta, xn);
  gemm_qkv_kernel<<<dim3(768, 4, 3), 256, 0, stream>>>(xn, Wb, Qb);
  attn_kernel<<<3072, 256, 0, stream>>>(Qb, Kb, Vb, x, out);
}